// Round 12
// baseline (90.529 us; speedup 1.0000x reference)
//
#include <hip/hip_runtime.h>

// 3D trilinear warp (grid_sample, align_corners=True, border padding).
// image: (B=2, 1, 160, 192, 192) f32 | ddf: (B,3,D,H,W) f32 (dz,dy,dx voxels)
//
// Round-12: R11 skeleton + batched LDS gathers + incremental staging stream.
//  - Grid 6 x 24 x 8 x 2 = 2304 blocks = exactly 9/CU, 1024 threads.
//  - Window: 32 slices [zlo-4, zlo+28) of a 52x23 region (153 KB), direct
//    slot mapping. Phase A stages slices [.., zlo+12); phase B issues the
//    rest into regs, committed after batch-A compute (T14).
//  - Unified incremental chunk stream: (si,row,col,gaddr) advance by
//    add+carry (no div/mod per chunk); LDS offset = A0f + 4c (linear).
//  - Batched compute: per batch, ALL offsets/weights -> ALL LDS reads into
//    rv[NV][8] (reg arrays, const-indexed) -> ALL blends. 5-wide MLP on the
//    ~120cy LDS latency instead of serial per-voxel chains.
//  - Single unsigned-min offset clamp (garbage-safe reads, discarded on
//    miss). Misses ride the payload queue -> global epilogue (L2-hot).

typedef float f32x4 __attribute__((ext_vector_type(4)));
typedef float f32x2 __attribute__((ext_vector_type(2)));

constexpr int D_ = 160, H_ = 192, W_ = 192;
constexpr int HW_ = H_ * W_;
constexpr int N_  = D_ * HW_;

constexpr int TX_ = 32, TY_ = 8;
constexpr int XT_ = W_ / TX_;               // 6
constexpr int YT_ = H_ / TY_;               // 24
constexpr int ZH_ = 8;
constexpr int ZRUN_ = D_ / ZH_;             // 20
constexpr int NBLK_ = XT_ * YT_ * ZH_ * 2;  // 2304 = 9 * 256 exactly

constexpr int RX_ = 52, RY_ = 23, NZ_ = 32;
constexpr int SLICE_ = RX_ * RY_;           // 1196 floats
constexpr int CPS_ = SLICE_ / 4;            // 299 chunks per slice
constexpr int LIM_ = NZ_ * SLICE_ - RX_ - 2;// 38218: max safe base offset
constexpr int QCAP_ = 512;
constexpr int DG_ = 3 * HW_ + 9 * W_ + 40;  // stream advance (floats)

__global__ __launch_bounds__(1024) void warp3d_kernel(
    const float* __restrict__ img,
    const float* __restrict__ ddf,
    float* __restrict__ out)
{
    __shared__ float tile[NZ_ * SLICE_];    // 153,088 B
    __shared__ f32x4 qdat[QCAP_];           // 8,192 B
    __shared__ int   qcount;

    constexpr int CPX = NBLK_ / 8;          // 288
    int bid = blockIdx.x;
    int swz = (bid & 7) * CPX + (bid >> 3);

    int tx = swz % XT_;  int t1 = swz / XT_;
    int ty = t1 % YT_;   int t2 = t1 / YT_;
    int zh = t2 % ZH_;   int b  = t2 / ZH_;

    int zlo = zh * ZRUN_;
    int vz0 = zlo - 4;                      // virtual window origin
    int rx = min(max(tx * TX_ - 8, 0), W_ - RX_);
    int ry = min(max(ty * TY_ - 7, 0), H_ - RY_);

    const float* im = img + (size_t)b * N_;
    const float* dp = ddf + (size_t)b * 3 * N_;
    float*       op = out + (size_t)b * N_;

    int tid = threadIdx.x;
    int xi = tid & 31;
    int yy = (tid >> 5) & 7;
    int zz = tid >> 8;                      // 0..3

    int x = tx * TX_ + xi;
    int y = ty * TY_ + yy;
    int s0 = ((zlo + zz) * H_ + y) * W_ + x;

    // ---- ddf loads for all 5 voxels (latency hides under staging) ----
    float ddzv[5], ddyv[5], ddxv[5];
#pragma unroll
    for (int k = 0; k < 5; ++k) {
        int s = s0 + k * 4 * HW_;
        ddzv[k] = __builtin_nontemporal_load(dp + s);
        ddyv[k] = __builtin_nontemporal_load(dp + N_ + s);
        ddxv[k] = __builtin_nontemporal_load(dp + 2 * N_ + s);
    }

    if (tid == 0) qcount = 0;

    // ---- unified incremental staging stream ----
    int pzA0  = max(0, vz0);
    int pz1   = min(D_, zlo + 28);
    int pcntA = (zlo + 12 - pzA0) * CPS_;
    int pcntT = (pz1 - pzA0) * CPS_;
    int A0f   = (pzA0 - vz0) * SLICE_;

    int c   = tid;
    int si0 = tid / CPS_;                   // one-time divides
    int rem = tid - si0 * CPS_;
    int row = rem / 13;
    int col = rem - row * 13;
    int g   = (pzA0 + si0) * HW_ + (ry + row) * W_ + rx + col * 4;

    auto advance = [&]() {
        c += 1024; g += DG_; col += 10; row += 9;
        if (col >= 13) { col -= 13; row += 1; g += W_ - 52; }
        if (row >= RY_) { row -= RY_; g += HW_ - RY_ * W_; }
    };

    // phase A: direct stage of slices [pzA0, zlo+12)
    while (c < pcntA) {
        *(f32x4*)&tile[A0f + 4 * c] = *(const f32x4*)(im + g);
        advance();
    }

    // phase B: issue remaining slices into registers (<=5 slots always)
    f32x4 bv0, bv1, bv2, bv3, bv4;
    int   bl0, bl1, bl2, bl3, bl4;
    bool  bm0, bm1, bm2, bm3, bm4;
#define ISSUE_SLOT(BV, BL, BM)                                          \
    BM = (c < pcntT);                                                   \
    BL = A0f + 4 * c;                                                   \
    if (BM) { BV = *(const f32x4*)(im + g); advance(); }
    ISSUE_SLOT(bv0, bl0, bm0)
    ISSUE_SLOT(bv1, bl1, bm1)
    ISSUE_SLOT(bv2, bl2, bm2)
    ISSUE_SLOT(bv3, bl3, bm3)
    ISSUE_SLOT(bv4, bl4, bm4)
#undef ISSUE_SLOT

    __syncthreads();

    // global gather (overflow + epilogue path)
    auto gglobal = [&](int vx, int vy, int vz,
                       float gdx, float gdy, float gdz) -> float {
        float ix = fminf(fmaxf((float)vx + gdx, 0.f), (float)(W_ - 1));
        float iy = fminf(fmaxf((float)vy + gdy, 0.f), (float)(H_ - 1));
        float iz = fminf(fmaxf((float)vz + gdz, 0.f), (float)(D_ - 1));
        int x0 = min((int)ix, W_ - 2);
        int y0 = min((int)iy, H_ - 2);
        int z0 = min((int)iz, D_ - 2);
        float wx = ix - (float)x0;
        float wy = iy - (float)y0;
        float wz = iz - (float)z0;
        const float* p = im + (z0 * HW_ + y0 * W_ + x0);
        f32x2 a = *(const f32x2*)(p);
        f32x2 cc = *(const f32x2*)(p + W_);
        f32x2 e = *(const f32x2*)(p + HW_);
        f32x2 f = *(const f32x2*)(p + HW_ + W_);
        float c00 = a.x + (a.y - a.x) * wx;
        float c01 = cc.x + (cc.y - cc.x) * wx;
        float c10 = e.x + (e.y - e.x) * wx;
        float c11 = f.x + (f.y - f.x) * wx;
        float c0 = c00 + (c01 - c00) * wy;
        float c1 = c10 + (c11 - c10) * wy;
        return c0 + (c1 - c0) * wz;
    };

    // batched process: offsets -> all LDS reads -> all blends
#define BATCH(NV, K0, UZTOP)                                            \
    {                                                                   \
        float bwx[NV], bwy[NV], bwz[NV];                                \
        int bo0[NV], bo1[NV], bsv[NV], bzv[NV];                         \
        unsigned binv[NV];                                              \
        _Pragma("unroll")                                               \
        for (int kk = 0; kk < NV; ++kk) {                               \
            int k = K0 + kk;                                            \
            int z = zlo + zz + 4 * k;                                   \
            bzv[kk] = z;                                                \
            bsv[kk] = s0 + k * 4 * HW_;                                 \
            float ix = fminf(fmaxf((float)x + ddxv[k], 0.f), (float)(W_ - 1)); \
            float iy = fminf(fmaxf((float)y + ddyv[k], 0.f), (float)(H_ - 1)); \
            float iz = fminf(fmaxf((float)z + ddzv[k], 0.f), (float)(D_ - 1)); \
            int x0 = min((int)ix, W_ - 2);                              \
            int y0 = min((int)iy, H_ - 2);                              \
            int z0 = min((int)iz, D_ - 2);                              \
            bwx[kk] = ix - (float)x0;                                   \
            bwy[kk] = iy - (float)y0;                                   \
            bwz[kk] = iz - (float)z0;                                   \
            int ux = x0 - rx, uy = y0 - ry, uz = z0 - vz0;              \
            binv[kk] = ((unsigned)ux <= (unsigned)(RX_ - 2)) &          \
                       ((unsigned)uy <= (unsigned)(RY_ - 2)) &          \
                       ((unsigned)uz <= (unsigned)(UZTOP));             \
            int o0r = uz * SLICE_ + uy * RX_ + ux;                      \
            int o0 = (int)min((unsigned)o0r, (unsigned)LIM_);           \
            bo0[kk] = o0;                                               \
            bo1[kk] = min(o0 + SLICE_, LIM_);                           \
        }                                                               \
        float rv[NV][8];                                                \
        _Pragma("unroll")                                               \
        for (int kk = 0; kk < NV; ++kk) {                               \
            int o0 = bo0[kk], o1 = bo1[kk];                             \
            rv[kk][0] = tile[o0];       rv[kk][1] = tile[o0 + 1];       \
            rv[kk][2] = tile[o0 + RX_]; rv[kk][3] = tile[o0 + RX_ + 1]; \
            rv[kk][4] = tile[o1];       rv[kk][5] = tile[o1 + 1];       \
            rv[kk][6] = tile[o1 + RX_]; rv[kk][7] = tile[o1 + RX_ + 1]; \
        }                                                               \
        _Pragma("unroll")                                               \
        for (int kk = 0; kk < NV; ++kk) {                               \
            int k = K0 + kk;                                            \
            float wx = bwx[kk], wy = bwy[kk], wz = bwz[kk];             \
            float c00 = rv[kk][0] + (rv[kk][1] - rv[kk][0]) * wx;       \
            float c01 = rv[kk][2] + (rv[kk][3] - rv[kk][2]) * wx;       \
            float c10 = rv[kk][4] + (rv[kk][5] - rv[kk][4]) * wx;       \
            float c11 = rv[kk][6] + (rv[kk][7] - rv[kk][6]) * wx;       \
            float c0 = c00 + (c01 - c00) * wy;                          \
            float c1 = c10 + (c11 - c10) * wy;                          \
            float res = c0 + (c1 - c0) * wz;                            \
            bool do_store = binv[kk] != 0u;                             \
            if (!do_store) {                                            \
                int idx = atomicAdd(&qcount, 1);                        \
                if (idx < QCAP_) {                                      \
                    qdat[idx] = f32x4{__int_as_float(bsv[kk]),          \
                                      ddxv[k], ddyv[k], ddzv[k]};       \
                } else {                                                \
                    res = gglobal(x, y, bzv[kk], ddxv[k], ddyv[k], ddzv[k]); \
                    do_store = true;                                    \
                }                                                       \
            }                                                           \
            if (do_store) __builtin_nontemporal_store(res, op + bsv[kk]); \
        }                                                               \
    }

    // ---- compute k=0,1 against phase-A window (slots 0..15 -> uz<=14) ----
    BATCH(2, 0, 14)

    // ---- commit phase-B regs to LDS slots 16..31 (disjoint from A reads) --
    if (bm0) *(f32x4*)&tile[bl0] = bv0;
    if (bm1) *(f32x4*)&tile[bl1] = bv1;
    if (bm2) *(f32x4*)&tile[bl2] = bv2;
    if (bm3) *(f32x4*)&tile[bl3] = bv3;
    if (bm4) *(f32x4*)&tile[bl4] = bv4;
    __syncthreads();

    // ---- compute k=2..4 with the full window (uz<=30) ----
    BATCH(3, 2, 30)
#undef BATCH

    __syncthreads();

    // ---- epilogue: resolve queued misses (ddf from queue, gathers L2-hot) --
    int n = min(qcount, QCAP_);
    for (int i = tid; i < n; i += 1024) {
        f32x4 q = qdat[i];
        int sq = __float_as_int(q.x);
        int zq = sq / HW_;
        int rq = sq - zq * HW_;
        int yq = rq / W_;
        int xq = rq - yq * W_;
        float res = gglobal(xq, yq, zq, q.y, q.z, q.w);
        op[sq] = res;
    }
}

extern "C" void kernel_launch(void* const* d_in, const int* in_sizes, int n_in,
                              void* d_out, int out_size, void* d_ws, size_t ws_size,
                              hipStream_t stream) {
    const float* img = (const float*)d_in[0];
    const float* ddf = (const float*)d_in[1];
    float*       out = (float*)d_out;

    warp3d_kernel<<<NBLK_, 1024, 0, stream>>>(img, ddf, out);
}